// Round 2
// baseline (61.546 us; speedup 1.0000x reference)
//
#include <hip/hip_runtime.h>
#include <hip/hip_bf16.h>

// Spline1DInterpolant: out[b] = sum_i c[i] * u(|s_b - (i+1)|), s_b = (x_b - a)/h + 2,
// h = (b - a)/n. u is a cubic B-spline with support |t| <= 2, so only the 4
// coefficients i in {floor(s)-2 .. floor(s)+1} (0-based) contribute. Exact
// sparse evaluation -- identical fp32 op ordering per surviving term.
//
// 4 queries per thread via float4 load/store; 64 blocks x 64 threads.
// Kernel is launch-overhead bound (all inputs L2-warm from harness restore).

__global__ __launch_bounds__(64) void spline1d_kernel(
    const float* __restrict__ x,
    const float* __restrict__ a,
    const float* __restrict__ b,
    const float* __restrict__ n,
    const float* __restrict__ c,
    float* __restrict__ out,
    int B, int C)
{
    const int q4 = blockIdx.x * blockDim.x + threadIdx.x; // float4 group index
    const int base = q4 * 4;
    if (base >= B) return;

    const float av = a[0];
    const float h  = (b[0] - av) / n[0];   // match reference: h = (b-a)/n, then (x-a)/h

    float4 xv;
    float r[4];

    if (base + 3 < B) {
        xv = *reinterpret_cast<const float4*>(x + base);
    } else {
        const float* xp = x + base;
        xv.x = xp[0];
        xv.y = (base + 1 < B) ? xp[1] : 0.0f;
        xv.z = (base + 2 < B) ? xp[2] : 0.0f;
        xv.w = 0.0f;
    }
    const float xs[4] = {xv.x, xv.y, xv.z, xv.w};

#pragma unroll
    for (int j = 0; j < 4; ++j) {
        const float s = (xs[j] - av) / h + 2.0f;
        const int i0 = (int)floorf(s) - 2; // first contributing 0-based coeff index
        float acc = 0.0f;
#pragma unroll
        for (int k = 0; k < 4; ++k) {
            const int i = i0 + k;
            const int ic = min(max(i, 0), C - 1);          // safe load index
            const float t = fabsf(s - (float)(i + 1));
            const float t2 = t * t;
            const float inner = 4.0f - 6.0f * t2 + 3.0f * t2 * t; // t <= 1
            const float om = 2.0f - t;
            const float outer = om * om * om;                     // 1 < t <= 2
            float u = (t <= 1.0f) ? inner : outer;
            u = (i >= 0 && i < C && t <= 2.0f) ? u : 0.0f;        // mask OOR / t>2
            acc += c[ic] * u;
        }
        r[j] = acc;
    }

    if (base + 3 < B) {
        *reinterpret_cast<float4*>(out + base) = make_float4(r[0], r[1], r[2], r[3]);
    } else {
        for (int j = 0; j < 4 && base + j < B; ++j) out[base + j] = r[j];
    }
}

extern "C" void kernel_launch(void* const* d_in, const int* in_sizes, int n_in,
                              void* d_out, int out_size, void* d_ws, size_t ws_size,
                              hipStream_t stream) {
    const float* x = (const float*)d_in[0];  // [B,1] -> B floats
    const float* a = (const float*)d_in[1];  // [1]
    const float* b = (const float*)d_in[2];  // [1]
    const float* n = (const float*)d_in[3];  // [1]
    const float* c = (const float*)d_in[4];  // [C]
    float* out = (float*)d_out;              // [B]

    const int B = in_sizes[0];
    const int C = in_sizes[4];

    const int block = 64;
    const int groups = (B + 3) / 4;          // float4 groups
    const int grid = (groups + block - 1) / block;
    spline1d_kernel<<<grid, block, 0, stream>>>(x, a, b, n, c, out, B, C);
}